// Round 1
// baseline (18.516 us; speedup 1.0000x reference)
//
#include <hip/hip_runtime.h>

#define POS_THR 0.7f
#define MAX_A 64

// One thread per (b, n). gt boxes for the block's batch staged in LDS.
// IoU computed with the reference's exact fp32 op order (clip = min(max(.)),
// true division) so the >= 0.7 compare matches numpy bit-for-bit.
__global__ __launch_bounds__(256) void assign_cls_kernel(
    const float4* __restrict__ bbox,    // [B, N] of (y1,x1,y2,x2)
    const float4* __restrict__ gt,      // [B, A]
    const int*    __restrict__ gt_counts, // [B]
    const int*    __restrict__ counts,    // [B]
    int*          __restrict__ out,       // [B, N]
    int N, int A)
{
    const int b = blockIdx.y;
    const int n = blockIdx.x * blockDim.x + threadIdx.x;

    __shared__ float4 sgt[MAX_A];
    __shared__ float  sga[MAX_A];
    if ((int)threadIdx.x < A) {
        float4 g = gt[(size_t)b * A + threadIdx.x];
        sgt[threadIdx.x] = g;
        // ga = (gy2 - gy1) * (gx2 - gx1)
        sga[threadIdx.x] = (g.z - g.x) * (g.w - g.y);
    }
    __syncthreads();

    if (n >= N) return;

    const int G   = min(gt_counts[b], A);  // only valid gt boxes matter
    const int cnt = counts[b];             // block-uniform: whole waves skip

    int label = 0;
    if (n < cnt) {
        const float4 bb = bbox[(size_t)b * N + n];  // y1,x1,y2,x2
        const float area = (bb.z - bb.x) * (bb.w - bb.y);
        for (int g = 0; g < G; ++g) {
            const float4 gb = sgt[g];
            // clip(v, lo, hi) = min(max(v, lo), hi) — same order as jnp.clip
            const float yy1 = fminf(fmaxf(bb.x, gb.x), gb.z);
            const float xx1 = fminf(fmaxf(bb.y, gb.y), gb.w);
            const float yy2 = fminf(fmaxf(bb.z, gb.x), gb.z);
            const float xx2 = fminf(fmaxf(bb.w, gb.y), gb.w);
            const float inter = (yy2 - yy1) * (xx2 - xx1);
            const float uni   = area + sga[g] - inter;
            if (inter / uni >= POS_THR) { label = 1; break; }
        }
    }
    out[(size_t)b * N + n] = label;
}

extern "C" void kernel_launch(void* const* d_in, const int* in_sizes, int n_in,
                              void* d_out, int out_size, void* d_ws, size_t ws_size,
                              hipStream_t stream) {
    const float4* bbox      = (const float4*)d_in[0];
    const float4* gt        = (const float4*)d_in[1];
    const int*    gt_counts = (const int*)d_in[2];
    const int*    counts    = (const int*)d_in[3];
    int*          out       = (int*)d_out;

    const int B = in_sizes[2];               // gt_counts has B elements
    const int A = in_sizes[1] / (4 * B);     // 64
    const int N = in_sizes[0] / (4 * B);     // 65536

    dim3 block(256, 1, 1);
    dim3 grid((N + 255) / 256, B, 1);
    assign_cls_kernel<<<grid, block, 0, stream>>>(bbox, gt, gt_counts, counts,
                                                  out, N, A);
}